// Round 8
// baseline (909.427 us; speedup 1.0000x reference)
//
#include <hip/hip_runtime.h>
#include <hip/hip_cooperative_groups.h>
#include <math.h>

namespace cg = cooperative_groups;

#define NN 50000
#define NE 800000
#define NG 50
#define F0 128
#define F1 64
#define F2 32
#define NPB 256                  // nodes per bucket (bucket = dst >> 8)
#define NBK 196                  // ceil(NN/NPB)
#define CHUNK 4096
#define NC 196                   // ceil(NE/CHUNK)
#define NCSR 196                 // blocks dedicated to CSR phases
#define NTILE1 1563              // ceil(NN/32)
#define NTILE2 782               // ceil(NN/64)
#define NBLK 512                 // 2 blocks/CU x 256 CUs (co-resident, wide margin)

__device__ __forceinline__ float lrelu(float v, float slope) {
    return v > 0.0f ? v : v * slope;
}

struct MegaParams {
    const float* x; const int* src; const int* dst; const int* gid;
    const float* W1; const float* al1; const float* ar1; const float* b1;
    const float* W2; const float* al2; const float* ar2; const float* b2;
    float* out;
    float* z1; float* h1; float* z2; float* h2; float* el; float* er;
    int* row_start; int* srcs; int* hist; int* btot; int* bstart;
    int2* part;
};

// ============================ mega (cooperative) ============================
__global__ __launch_bounds__(256, 2) void mega_kernel(MegaParams P)
{
    cg::grid_group grid = cg::this_grid();
    const int tid = threadIdx.x;
    const int bid = blockIdx.x;
    const int nblk = gridDim.x;
    __shared__ __align__(16) char smraw[49152];   // 48 KB union

    // ---- phase 0: CSR p1 hist (blocks<NCSR)  ||  gemm1 (rest) ----
    if (bid < NCSR) {
        int* h = (int*)smraw;
        for (int c = bid; c < NC; c += NCSR) {
            if (tid < NBK) h[tid] = 0;
            __syncthreads();
            int e0 = c * CHUNK;
            int e1 = (e0 + CHUNK < NE) ? e0 + CHUNK : NE;
            for (int e = e0 + tid; e < e1; e += 256)
                atomicAdd(&h[P.dst[e] >> 8], 1);
            __syncthreads();
            if (tid < NBK) P.hist[tid * NC + c] = h[tid];
            __syncthreads();
        }
    } else {
        float* Ws = (float*)smraw;                              // 32 KB
        float (*xs)[F0] = (float (*)[F0])(smraw + F0 * F1 * 4); // 16 KB
        const float4* W4 = (const float4*)P.W1;
        float4* Ws4 = (float4*)Ws;
        #pragma unroll
        for (int i = 0; i < 8; ++i) Ws4[tid + i * 256] = W4[tid + i * 256];
        __syncthreads();
        int j = tid & 63, rg = tid >> 6;
        float a_l = P.al1[j], a_r = P.ar1[j];
        for (int tile = bid - NCSR; tile < NTILE1; tile += nblk - NCSR) {
            int r0 = tile * 32;
            float4 zero = {0.f, 0.f, 0.f, 0.f};
            #pragma unroll
            for (int i2 = 0; i2 < 4; ++i2) {
                int s = tid + i2 * 256;
                int row = s >> 5, c4 = s & 31;
                int grow = r0 + row;
                float4 v = (grow < NN)
                    ? ((const float4*)P.x)[(size_t)grow * 32 + c4] : zero;
                *(float4*)&xs[row][c4 * 4] = v;
            }
            __syncthreads();
            float acc[8] = {0.f, 0.f, 0.f, 0.f, 0.f, 0.f, 0.f, 0.f};
            for (int k4 = 0; k4 < F0 / 4; ++k4) {
                float w0 = Ws[(k4 * 4 + 0) * F1 + j];
                float w1 = Ws[(k4 * 4 + 1) * F1 + j];
                float w2 = Ws[(k4 * 4 + 2) * F1 + j];
                float w3 = Ws[(k4 * 4 + 3) * F1 + j];
                #pragma unroll
                for (int r = 0; r < 8; ++r) {
                    float4 xv = *(const float4*)&xs[rg * 8 + r][k4 * 4];
                    acc[r] = fmaf(xv.x, w0, fmaf(xv.y, w1, fmaf(xv.z, w2, fmaf(xv.w, w3, acc[r]))));
                }
            }
            #pragma unroll
            for (int r = 0; r < 8; ++r) {
                int row = r0 + rg * 8 + r;
                if (row < NN) P.z1[(size_t)row * F1 + j] = acc[r];
                float pl = acc[r] * a_l, pr = acc[r] * a_r;
                #pragma unroll
                for (int mm = 1; mm < 64; mm <<= 1) {
                    pl += __shfl_xor(pl, mm);
                    pr += __shfl_xor(pr, mm);
                }
                if (j == 0 && row < NN) { P.el[row] = pl; P.er[row] = pr; }
            }
            __syncthreads();
        }
    }
    grid.sync();

    // ---- phase 1: per-bucket scan over chunks (blocks < NBK) ----
    if (bid < NBK) {
        int* t = (int*)smraw;
        int v = (tid < NC) ? P.hist[bid * NC + tid] : 0;
        t[tid] = v;
        __syncthreads();
        for (int off = 1; off < 256; off <<= 1) {
            int u = (tid >= off) ? t[tid - off] : 0;
            __syncthreads();
            t[tid] += u;
            __syncthreads();
        }
        if (tid < NC) P.hist[bid * NC + tid] = t[tid] - v;  // exclusive
        if (tid == 255) P.btot[bid] = t[255];
    }
    grid.sync();

    // ---- phase 2: bucket-base scan (block 0) ----
    if (bid == 0) {
        int* t = (int*)smraw;
        int v = (tid < NBK) ? P.btot[tid] : 0;
        t[tid] = v;
        __syncthreads();
        for (int off = 1; off < 256; off <<= 1) {
            int u = (tid >= off) ? t[tid - off] : 0;
            __syncthreads();
            t[tid] += u;
            __syncthreads();
        }
        if (tid < NBK) P.bstart[tid] = t[tid] - v;
        if (tid == NBK) P.bstart[NBK] = NE;
        if (tid == 0) P.row_start[NN] = NE;
    }
    grid.sync();

    // ---- phase 3: partition into bucket-contiguous (src,dst) ----
    if (bid < NCSR) {
        int* base = (int*)smraw;
        int* cnt  = base + NBK;
        for (int cc = bid; cc < NC; cc += NCSR) {
            if (tid < NBK) {
                base[tid] = P.hist[tid * NC + cc] + P.bstart[tid];
                cnt[tid] = 0;
            }
            __syncthreads();
            int e0 = cc * CHUNK;
            int e1 = (e0 + CHUNK < NE) ? e0 + CHUNK : NE;
            for (int e = e0 + tid; e < e1; e += 256) {
                int s = P.src[e], d = P.dst[e];
                int b = d >> 8;
                int r = atomicAdd(&cnt[b], 1);
                P.part[base[b] + r] = make_int2(s, d);
            }
            __syncthreads();
        }
    }
    grid.sync();

    // ---- phase 4: per-bucket rank -> row_start + srcs ----
    if (bid < NBK) {
        int* deg = (int*)smraw;
        int* off = deg + NPB;
        int* cnt = off + NPB;
        int lo = P.bstart[bid], hi = P.bstart[bid + 1];
        deg[tid] = 0;
        cnt[tid] = 0;
        __syncthreads();
        for (int i = lo + tid; i < hi; i += 256)
            atomicAdd(&deg[P.part[i].y & (NPB - 1)], 1);
        __syncthreads();
        int v = deg[tid];
        off[tid] = v;
        __syncthreads();
        for (int o = 1; o < 256; o <<= 1) {
            int u = (tid >= o) ? off[tid - o] : 0;
            __syncthreads();
            off[tid] += u;
            __syncthreads();
        }
        int ex = off[tid] - v;
        __syncthreads();
        off[tid] = ex;
        __syncthreads();
        int node = bid * NPB + tid;
        if (node < NN) P.row_start[node] = lo + ex;
        for (int i = lo + tid; i < hi; i += 256) {
            int2 e = P.part[i];
            int n = e.y & (NPB - 1);
            int r = atomicAdd(&cnt[n], 1);
            P.srcs[lo + off[n] + r] = e.x;
        }
    }
    grid.sync();

    // ---- phase 5: GAT aggregation layer 1 (F=64, wave/node) ----
    {
        const float4* z4 = (const float4*)P.z1;
        int lane = tid & 63;
        int w = tid >> 6;
        int g = lane >> 4, c = lane & 15;
        for (int node = bid * 4 + w; node < NN; node += nblk * 4) {
            int beg = P.row_start[node], end = P.row_start[node + 1];
            float erd = P.er[node];
            int i0 = beg + lane;
            float v0 = -INFINITY;
            if (i0 < end) v0 = lrelu(P.el[P.srcs[i0]] + erd, 0.2f);
            float lm = v0;
            for (int i = i0 + 64; i < end; i += 64)
                lm = fmaxf(lm, lrelu(P.el[P.srcs[i]] + erd, 0.2f));
            #pragma unroll
            for (int mm = 1; mm < 64; mm <<= 1) lm = fmaxf(lm, __shfl_xor(lm, mm));
            float preg = 0.f, ls = 0.f;
            if (i0 < end) { preg = __expf(v0 - lm); ls = preg; }
            for (int i = i0 + 64; i < end; i += 64)
                ls += __expf(lrelu(P.el[P.srcs[i]] + erd, 0.2f) - lm);
            #pragma unroll
            for (int mm = 1; mm < 64; mm <<= 1) ls += __shfl_xor(ls, mm);
            float inv_s = (ls > 0.f) ? 1.0f / ls : 0.f;

            float4 acc = {0.f, 0.f, 0.f, 0.f};
            int ib = beg;
            for (; ib + 8 <= end; ib += 8) {
                int ia = ib + g, ic = ib + 4 + g;
                int ja = ia - beg, jc = ic - beg;
                float pva = __shfl(preg, ja & 63);
                float pvc = __shfl(preg, jc & 63);
                int sna = P.srcs[ia], snc = P.srcs[ic];
                if (ja >= 64) pva = __expf(lrelu(P.el[sna] + erd, 0.2f) - lm);
                if (jc >= 64) pvc = __expf(lrelu(P.el[snc] + erd, 0.2f) - lm);
                float4 zva = z4[(size_t)sna * 16 + c];
                float4 zvc = z4[(size_t)snc * 16 + c];
                float aa = pva * inv_s, ac = pvc * inv_s;
                acc.x = fmaf(aa, zva.x, fmaf(ac, zvc.x, acc.x));
                acc.y = fmaf(aa, zva.y, fmaf(ac, zvc.y, acc.y));
                acc.z = fmaf(aa, zva.z, fmaf(ac, zvc.z, acc.z));
                acc.w = fmaf(aa, zva.w, fmaf(ac, zvc.w, acc.w));
            }
            for (; ib < end; ib += 4) {
                int i = ib + g, jj = i - beg;
                float pv = __shfl(preg, jj & 63);
                if (i < end) {
                    int sn = P.srcs[i];
                    if (jj >= 64) pv = __expf(lrelu(P.el[sn] + erd, 0.2f) - lm);
                    float alpha = pv * inv_s;
                    float4 zv = z4[(size_t)sn * 16 + c];
                    acc.x = fmaf(alpha, zv.x, acc.x);
                    acc.y = fmaf(alpha, zv.y, acc.y);
                    acc.z = fmaf(alpha, zv.z, acc.z);
                    acc.w = fmaf(alpha, zv.w, acc.w);
                }
            }
            #pragma unroll
            for (int mm = 16; mm < 64; mm <<= 1) {
                acc.x += __shfl_xor(acc.x, mm);
                acc.y += __shfl_xor(acc.y, mm);
                acc.z += __shfl_xor(acc.z, mm);
                acc.w += __shfl_xor(acc.w, mm);
            }
            if (g == 0) {
                float4 bb = ((const float4*)P.b1)[c];
                float4 o;
                o.x = lrelu(acc.x + bb.x, 0.01f);
                o.y = lrelu(acc.y + bb.y, 0.01f);
                o.z = lrelu(acc.z + bb.z, 0.01f);
                o.w = lrelu(acc.w + bb.w, 0.01f);
                ((float4*)P.h1)[(size_t)node * 16 + c] = o;
            }
        }
    }
    grid.sync();

    // ---- phase 6: GEMM2 (64-row tiles, all blocks) ----
    {
        float* Ws = (float*)smraw;                              // 8 KB
        float (*xs)[F1] = (float (*)[F1])(smraw + F1 * F2 * 4); // 16 KB
        const float4* W4 = (const float4*)P.W2;
        float4* Ws4 = (float4*)Ws;
        #pragma unroll
        for (int i = 0; i < 2; ++i) Ws4[tid + i * 256] = W4[tid + i * 256];
        __syncthreads();
        int j = tid & 31, rg = tid >> 5;
        float a_l = P.al2[j], a_r = P.ar2[j];
        for (int tile = bid; tile < NTILE2; tile += nblk) {
            int r0 = tile * 64;
            float4 zero = {0.f, 0.f, 0.f, 0.f};
            #pragma unroll
            for (int i2 = 0; i2 < 4; ++i2) {
                int s = tid + i2 * 256;
                int row = s >> 4, c4 = s & 15;
                int grow = r0 + row;
                float4 v = (grow < NN)
                    ? ((const float4*)P.h1)[(size_t)grow * 16 + c4] : zero;
                *(float4*)&xs[row][c4 * 4] = v;
            }
            __syncthreads();
            float acc[8] = {0.f, 0.f, 0.f, 0.f, 0.f, 0.f, 0.f, 0.f};
            for (int k4 = 0; k4 < F1 / 4; ++k4) {
                float w0 = Ws[(k4 * 4 + 0) * F2 + j];
                float w1 = Ws[(k4 * 4 + 1) * F2 + j];
                float w2 = Ws[(k4 * 4 + 2) * F2 + j];
                float w3 = Ws[(k4 * 4 + 3) * F2 + j];
                #pragma unroll
                for (int r = 0; r < 8; ++r) {
                    float4 xv = *(const float4*)&xs[rg * 8 + r][k4 * 4];
                    acc[r] = fmaf(xv.x, w0, fmaf(xv.y, w1, fmaf(xv.z, w2, fmaf(xv.w, w3, acc[r]))));
                }
            }
            #pragma unroll
            for (int r = 0; r < 8; ++r) {
                int row = r0 + rg * 8 + r;
                if (row < NN) P.z2[(size_t)row * F2 + j] = acc[r];
                float pl = acc[r] * a_l, pr = acc[r] * a_r;
                #pragma unroll
                for (int mm = 1; mm < 32; mm <<= 1) {
                    pl += __shfl_xor(pl, mm);
                    pr += __shfl_xor(pr, mm);
                }
                if (j == 0 && row < NN) { P.el[row] = pl; P.er[row] = pr; }
            }
            __syncthreads();
        }
    }
    grid.sync();

    // ---- phase 7: GAT aggregation layer 2 (F=32, half-wave/node) ----
    {
        const float4* z4 = (const float4*)P.z2;
        int sub = tid & 31;
        int base = tid & 32;
        int hw = tid >> 5;
        int g = sub >> 3, c = sub & 7;
        for (int node = bid * 8 + hw; node < NN; node += nblk * 8) {
            int beg = P.row_start[node], end = P.row_start[node + 1];
            float erd = P.er[node];
            int i0 = beg + sub;
            float v0 = -INFINITY;
            if (i0 < end) v0 = lrelu(P.el[P.srcs[i0]] + erd, 0.2f);
            float lm = v0;
            for (int i = i0 + 32; i < end; i += 32)
                lm = fmaxf(lm, lrelu(P.el[P.srcs[i]] + erd, 0.2f));
            #pragma unroll
            for (int mm = 1; mm < 32; mm <<= 1) lm = fmaxf(lm, __shfl_xor(lm, mm));
            float preg = 0.f, ls = 0.f;
            if (i0 < end) { preg = __expf(v0 - lm); ls = preg; }
            for (int i = i0 + 32; i < end; i += 32)
                ls += __expf(lrelu(P.el[P.srcs[i]] + erd, 0.2f) - lm);
            #pragma unroll
            for (int mm = 1; mm < 32; mm <<= 1) ls += __shfl_xor(ls, mm);
            float inv_s = (ls > 0.f) ? 1.0f / ls : 0.f;

            float4 acc = {0.f, 0.f, 0.f, 0.f};
            int ib = beg;
            for (; ib + 8 <= end; ib += 8) {
                int ia = ib + g, ic = ib + 4 + g;
                int ja = ia - beg, jc = ic - beg;
                float pva = __shfl(preg, base | (ja & 31));
                float pvc = __shfl(preg, base | (jc & 31));
                int sna = P.srcs[ia], snc = P.srcs[ic];
                if (ja >= 32) pva = __expf(lrelu(P.el[sna] + erd, 0.2f) - lm);
                if (jc >= 32) pvc = __expf(lrelu(P.el[snc] + erd, 0.2f) - lm);
                float4 zva = z4[(size_t)sna * 8 + c];
                float4 zvc = z4[(size_t)snc * 8 + c];
                float aa = pva * inv_s, ac = pvc * inv_s;
                acc.x = fmaf(aa, zva.x, fmaf(ac, zvc.x, acc.x));
                acc.y = fmaf(aa, zva.y, fmaf(ac, zvc.y, acc.y));
                acc.z = fmaf(aa, zva.z, fmaf(ac, zvc.z, acc.z));
                acc.w = fmaf(aa, zva.w, fmaf(ac, zvc.w, acc.w));
            }
            for (; ib < end; ib += 4) {
                int i = ib + g, jj = i - beg;
                float pv = __shfl(preg, base | (jj & 31));
                if (i < end) {
                    int sn = P.srcs[i];
                    if (jj >= 32) pv = __expf(lrelu(P.el[sn] + erd, 0.2f) - lm);
                    float alpha = pv * inv_s;
                    float4 zv = z4[(size_t)sn * 8 + c];
                    acc.x = fmaf(alpha, zv.x, acc.x);
                    acc.y = fmaf(alpha, zv.y, acc.y);
                    acc.z = fmaf(alpha, zv.z, acc.z);
                    acc.w = fmaf(alpha, zv.w, acc.w);
                }
            }
            #pragma unroll
            for (int mm = 8; mm < 32; mm <<= 1) {
                acc.x += __shfl_xor(acc.x, mm);
                acc.y += __shfl_xor(acc.y, mm);
                acc.z += __shfl_xor(acc.z, mm);
                acc.w += __shfl_xor(acc.w, mm);
            }
            if (g == 0) {
                float4 bb = ((const float4*)P.b2)[c];
                float4 o;
                o.x = lrelu(acc.x + bb.x, 0.01f);
                o.y = lrelu(acc.y + bb.y, 0.01f);
                o.z = lrelu(acc.z + bb.z, 0.01f);
                o.w = lrelu(acc.w + bb.w, 0.01f);
                ((float4*)P.h2)[(size_t)node * 8 + c] = o;
            }
        }
    }
    grid.sync();

    // ---- phase 8: per-graph mean pool (blocks < NG) ----
    if (bid < NG) {
        float* red = (float*)smraw;
        int g = bid;
        int lo = 0, hi = NN;
        while (lo < hi) { int mid = (lo + hi) >> 1; if (P.gid[mid] < g) lo = mid + 1; else hi = mid; }
        int start = lo;
        hi = NN;
        while (lo < hi) { int mid = (lo + hi) >> 1; if (P.gid[mid] < g + 1) lo = mid + 1; else hi = mid; }
        int end = lo;
        int f = tid & 31, r = tid >> 5;
        float acc = 0.f;
        for (int n = start + r; n < end; n += 8) acc += P.h2[(size_t)n * F2 + f];
        red[tid] = acc;
        __syncthreads();
        for (int st = 128; st >= 32; st >>= 1) {
            if (tid < st) red[tid] += red[tid + st];
            __syncthreads();
        }
        if (tid < 32) {
            float cnt = (float)(end - start);
            P.out[g * F2 + tid] = red[tid] / fmaxf(cnt, 1.0f);
        }
    }
}

// ===================== fallback kernels (round-5 pipeline) ==================

__global__ __launch_bounds__(256) void gemm1_kernel(
    const float* __restrict__ x, const float* __restrict__ W,
    const float* __restrict__ al, const float* __restrict__ ar,
    float* __restrict__ z, float* __restrict__ el, float* __restrict__ er)
{
    __shared__ float Ws[F0 * F1];
    __shared__ float xs[32][F0];
    int tid = threadIdx.x;
    int r0 = blockIdx.x * 32;
    {
        const float4* W4 = reinterpret_cast<const float4*>(W);
        float4* Ws4 = reinterpret_cast<float4*>(Ws);
        #pragma unroll
        for (int i = 0; i < 8; ++i) Ws4[tid + i * 256] = W4[tid + i * 256];
    }
    {
        float4 zero = {0.f, 0.f, 0.f, 0.f};
        #pragma unroll
        for (int i = 0; i < 4; ++i) {
            int s = tid + i * 256;
            int row = s >> 5, c4 = s & 31;
            int grow = r0 + row;
            float4 v = (grow < NN)
                ? reinterpret_cast<const float4*>(x)[(size_t)grow * 32 + c4] : zero;
            *reinterpret_cast<float4*>(&xs[row][c4 * 4]) = v;
        }
    }
    __syncthreads();
    int j = tid & 63, rg = tid >> 6;
    float acc[8] = {0.f, 0.f, 0.f, 0.f, 0.f, 0.f, 0.f, 0.f};
    for (int k4 = 0; k4 < F0 / 4; ++k4) {
        float w0 = Ws[(k4 * 4 + 0) * F1 + j];
        float w1 = Ws[(k4 * 4 + 1) * F1 + j];
        float w2 = Ws[(k4 * 4 + 2) * F1 + j];
        float w3 = Ws[(k4 * 4 + 3) * F1 + j];
        #pragma unroll
        for (int r = 0; r < 8; ++r) {
            float4 xv = *reinterpret_cast<const float4*>(&xs[rg * 8 + r][k4 * 4]);
            acc[r] = fmaf(xv.x, w0, fmaf(xv.y, w1, fmaf(xv.z, w2, fmaf(xv.w, w3, acc[r]))));
        }
    }
    float a_l = al[j], a_r = ar[j];
    #pragma unroll
    for (int r = 0; r < 8; ++r) {
        int row = r0 + rg * 8 + r;
        if (row < NN) z[(size_t)row * F1 + j] = acc[r];
        float pl = acc[r] * a_l, pr = acc[r] * a_r;
        #pragma unroll
        for (int mm = 1; mm < 64; mm <<= 1) {
            pl += __shfl_xor(pl, mm);
            pr += __shfl_xor(pr, mm);
        }
        if (j == 0 && row < NN) { el[row] = pl; er[row] = pr; }
    }
}

__global__ __launch_bounds__(256) void gemm2_kernel(
    const float* __restrict__ h, const float* __restrict__ W,
    const float* __restrict__ al, const float* __restrict__ ar,
    float* __restrict__ z, float* __restrict__ el, float* __restrict__ er)
{
    __shared__ float Ws[F1 * F2];
    __shared__ float xs[64][F1];
    int tid = threadIdx.x;
    int r0 = blockIdx.x * 64;
    {
        const float4* W4 = reinterpret_cast<const float4*>(W);
        float4* Ws4 = reinterpret_cast<float4*>(Ws);
        #pragma unroll
        for (int i = 0; i < 2; ++i) Ws4[tid + i * 256] = W4[tid + i * 256];
    }
    {
        float4 zero = {0.f, 0.f, 0.f, 0.f};
        #pragma unroll
        for (int i = 0; i < 4; ++i) {
            int s = tid + i * 256;
            int row = s >> 4, c4 = s & 15;
            int grow = r0 + row;
            float4 v = (grow < NN)
                ? reinterpret_cast<const float4*>(h)[(size_t)grow * 16 + c4] : zero;
            *reinterpret_cast<float4*>(&xs[row][c4 * 4]) = v;
        }
    }
    __syncthreads();
    int j = tid & 31, rg = tid >> 5;
    float acc[8] = {0.f, 0.f, 0.f, 0.f, 0.f, 0.f, 0.f, 0.f};
    for (int k4 = 0; k4 < F1 / 4; ++k4) {
        float w0 = Ws[(k4 * 4 + 0) * F2 + j];
        float w1 = Ws[(k4 * 4 + 1) * F2 + j];
        float w2 = Ws[(k4 * 4 + 2) * F2 + j];
        float w3 = Ws[(k4 * 4 + 3) * F2 + j];
        #pragma unroll
        for (int r = 0; r < 8; ++r) {
            float4 xv = *reinterpret_cast<const float4*>(&xs[rg * 8 + r][k4 * 4]);
            acc[r] = fmaf(xv.x, w0, fmaf(xv.y, w1, fmaf(xv.z, w2, fmaf(xv.w, w3, acc[r]))));
        }
    }
    float a_l = al[j], a_r = ar[j];
    #pragma unroll
    for (int r = 0; r < 8; ++r) {
        int row = r0 + rg * 8 + r;
        if (row < NN) z[(size_t)row * F2 + j] = acc[r];
        float pl = acc[r] * a_l, pr = acc[r] * a_r;
        #pragma unroll
        for (int mm = 1; mm < 32; mm <<= 1) {
            pl += __shfl_xor(pl, mm);
            pr += __shfl_xor(pr, mm);
        }
        if (j == 0 && row < NN) { el[row] = pl; er[row] = pr; }
    }
}

__global__ __launch_bounds__(256) void p1_hist_kernel(
    const int* __restrict__ dst, int* __restrict__ hist)
{
    __shared__ int h[NBK];
    int c = blockIdx.x;
    if (threadIdx.x < NBK) h[threadIdx.x] = 0;
    __syncthreads();
    int e0 = c * CHUNK;
    int e1 = (e0 + CHUNK < NE) ? e0 + CHUNK : NE;
    for (int e = e0 + threadIdx.x; e < e1; e += 256)
        atomicAdd(&h[dst[e] >> 8], 1);
    __syncthreads();
    if (threadIdx.x < NBK) hist[threadIdx.x * NC + c] = h[threadIdx.x];
}

__global__ __launch_bounds__(256) void p2a_scan_kernel(
    int* __restrict__ hist, int* __restrict__ btot)
{
    __shared__ int t[256];
    int b = blockIdx.x;
    int v = (threadIdx.x < NC) ? hist[b * NC + threadIdx.x] : 0;
    t[threadIdx.x] = v;
    __syncthreads();
    for (int off = 1; off < 256; off <<= 1) {
        int u = (threadIdx.x >= off) ? t[threadIdx.x - off] : 0;
        __syncthreads();
        t[threadIdx.x] += u;
        __syncthreads();
    }
    if (threadIdx.x < NC) hist[b * NC + threadIdx.x] = t[threadIdx.x] - v;
    if (threadIdx.x == 255) btot[b] = t[255];
}

__global__ __launch_bounds__(256) void p2b_scan_kernel(
    const int* __restrict__ btot, int* __restrict__ bstart, int* __restrict__ row_start)
{
    __shared__ int t[256];
    int v = (threadIdx.x < NBK) ? btot[threadIdx.x] : 0;
    t[threadIdx.x] = v;
    __syncthreads();
    for (int off = 1; off < 256; off <<= 1) {
        int u = (threadIdx.x >= off) ? t[threadIdx.x - off] : 0;
        __syncthreads();
        t[threadIdx.x] += u;
        __syncthreads();
    }
    if (threadIdx.x < NBK) bstart[threadIdx.x] = t[threadIdx.x] - v;
    if (threadIdx.x == NBK) bstart[NBK] = NE;
    if (threadIdx.x == 0) row_start[NN] = NE;
}

__global__ __launch_bounds__(256) void p3_part_kernel(
    const int* __restrict__ src, const int* __restrict__ dst,
    const int* __restrict__ hist, const int* __restrict__ bstart,
    int2* __restrict__ part)
{
    __shared__ int base[NBK];
    __shared__ int cnt[NBK];
    int c = blockIdx.x;
    if (threadIdx.x < NBK) {
        base[threadIdx.x] = hist[threadIdx.x * NC + c] + bstart[threadIdx.x];
        cnt[threadIdx.x] = 0;
    }
    __syncthreads();
    int e0 = c * CHUNK;
    int e1 = (e0 + CHUNK < NE) ? e0 + CHUNK : NE;
    for (int e = e0 + threadIdx.x; e < e1; e += 256) {
        int s = src[e], d = dst[e];
        int b = d >> 8;
        int r = atomicAdd(&cnt[b], 1);
        part[base[b] + r] = make_int2(s, d);
    }
}

__global__ __launch_bounds__(256) void p4_fill_kernel(
    const int2* __restrict__ part, const int* __restrict__ bstart,
    int* __restrict__ row_start, int* __restrict__ srcs)
{
    __shared__ int deg[NPB];
    __shared__ int off[NPB];
    __shared__ int cnt[NPB];
    int b = blockIdx.x;
    int lo = bstart[b], hi = bstart[b + 1];
    deg[threadIdx.x] = 0;
    cnt[threadIdx.x] = 0;
    __syncthreads();
    for (int i = lo + threadIdx.x; i < hi; i += 256)
        atomicAdd(&deg[part[i].y & (NPB - 1)], 1);
    __syncthreads();
    int v = deg[threadIdx.x];
    off[threadIdx.x] = v;
    __syncthreads();
    for (int o = 1; o < 256; o <<= 1) {
        int u = (threadIdx.x >= o) ? off[threadIdx.x - o] : 0;
        __syncthreads();
        off[threadIdx.x] += u;
        __syncthreads();
    }
    int ex = off[threadIdx.x] - v;
    __syncthreads();
    off[threadIdx.x] = ex;
    __syncthreads();
    int node = b * NPB + threadIdx.x;
    if (node < NN) row_start[node] = lo + ex;
    for (int i = lo + threadIdx.x; i < hi; i += 256) {
        int2 e = part[i];
        int n = e.y & (NPB - 1);
        int r = atomicAdd(&cnt[n], 1);
        srcs[lo + off[n] + r] = e.x;
    }
}

__global__ __launch_bounds__(256) void gat_agg64_kernel(
    const int* __restrict__ row_start, const int* __restrict__ srcs,
    const float* __restrict__ el, const float* __restrict__ er,
    const float* __restrict__ z, const float* __restrict__ b,
    float* __restrict__ out, float slope_out)
{
    int node = (blockIdx.x * 256 + threadIdx.x) >> 6;
    if (node >= NN) return;
    int lane = threadIdx.x & 63;
    int g = lane >> 4, c = lane & 15;
    int beg = row_start[node], end = row_start[node + 1];
    float erd = er[node];
    int i0 = beg + lane;
    float v0 = -INFINITY;
    if (i0 < end) v0 = lrelu(el[srcs[i0]] + erd, 0.2f);
    float lm = v0;
    for (int i = i0 + 64; i < end; i += 64)
        lm = fmaxf(lm, lrelu(el[srcs[i]] + erd, 0.2f));
    #pragma unroll
    for (int mm = 1; mm < 64; mm <<= 1) lm = fmaxf(lm, __shfl_xor(lm, mm));
    float preg = 0.f, ls = 0.f;
    if (i0 < end) { preg = __expf(v0 - lm); ls = preg; }
    for (int i = i0 + 64; i < end; i += 64)
        ls += __expf(lrelu(el[srcs[i]] + erd, 0.2f) - lm);
    #pragma unroll
    for (int mm = 1; mm < 64; mm <<= 1) ls += __shfl_xor(ls, mm);
    float inv_s = (ls > 0.f) ? 1.0f / ls : 0.f;
    const float4* z4 = reinterpret_cast<const float4*>(z);
    float4 acc = {0.f, 0.f, 0.f, 0.f};
    for (int ib = beg; ib < end; ib += 4) {
        int i = ib + g;
        int j = i - beg;
        float pv = __shfl(preg, j & 63);
        if (i < end) {
            int sn = srcs[i];
            if (j >= 64) pv = __expf(lrelu(el[sn] + erd, 0.2f) - lm);
            float alpha = pv * inv_s;
            float4 zv = z4[(size_t)sn * 16 + c];
            acc.x = fmaf(alpha, zv.x, acc.x);
            acc.y = fmaf(alpha, zv.y, acc.y);
            acc.z = fmaf(alpha, zv.z, acc.z);
            acc.w = fmaf(alpha, zv.w, acc.w);
        }
    }
    #pragma unroll
    for (int mm = 16; mm < 64; mm <<= 1) {
        acc.x += __shfl_xor(acc.x, mm);
        acc.y += __shfl_xor(acc.y, mm);
        acc.z += __shfl_xor(acc.z, mm);
        acc.w += __shfl_xor(acc.w, mm);
    }
    if (g == 0) {
        float4 bb = reinterpret_cast<const float4*>(b)[c];
        float4 o;
        o.x = lrelu(acc.x + bb.x, slope_out);
        o.y = lrelu(acc.y + bb.y, slope_out);
        o.z = lrelu(acc.z + bb.z, slope_out);
        o.w = lrelu(acc.w + bb.w, slope_out);
        reinterpret_cast<float4*>(out)[(size_t)node * 16 + c] = o;
    }
}

__global__ __launch_bounds__(256) void gat_agg32_kernel(
    const int* __restrict__ row_start, const int* __restrict__ srcs,
    const float* __restrict__ el, const float* __restrict__ er,
    const float* __restrict__ z, const float* __restrict__ b,
    float* __restrict__ out, float slope_out)
{
    int node = (blockIdx.x * 256 + threadIdx.x) >> 5;
    if (node >= NN) return;
    int sub = threadIdx.x & 31;
    int base = threadIdx.x & 32;
    int g = sub >> 3, c = sub & 7;
    int beg = row_start[node], end = row_start[node + 1];
    float erd = er[node];
    int i0 = beg + sub;
    float v0 = -INFINITY;
    if (i0 < end) v0 = lrelu(el[srcs[i0]] + erd, 0.2f);
    float lm = v0;
    for (int i = i0 + 32; i < end; i += 32)
        lm = fmaxf(lm, lrelu(el[srcs[i]] + erd, 0.2f));
    #pragma unroll
    for (int mm = 1; mm < 32; mm <<= 1) lm = fmaxf(lm, __shfl_xor(lm, mm));
    float preg = 0.f, ls = 0.f;
    if (i0 < end) { preg = __expf(v0 - lm); ls = preg; }
    for (int i = i0 + 32; i < end; i += 32)
        ls += __expf(lrelu(el[srcs[i]] + erd, 0.2f) - lm);
    #pragma unroll
    for (int mm = 1; mm < 32; mm <<= 1) ls += __shfl_xor(ls, mm);
    float inv_s = (ls > 0.f) ? 1.0f / ls : 0.f;
    const float4* z4 = reinterpret_cast<const float4*>(z);
    float4 acc = {0.f, 0.f, 0.f, 0.f};
    for (int ib = beg; ib < end; ib += 4) {
        int i = ib + g;
        int j = i - beg;
        float pv = __shfl(preg, base | (j & 31));
        if (i < end) {
            int sn = srcs[i];
            if (j >= 32) pv = __expf(lrelu(el[sn] + erd, 0.2f) - lm);
            float alpha = pv * inv_s;
            float4 zv = z4[(size_t)sn * 8 + c];
            acc.x = fmaf(alpha, zv.x, acc.x);
            acc.y = fmaf(alpha, zv.y, acc.y);
            acc.z = fmaf(alpha, zv.z, acc.z);
            acc.w = fmaf(alpha, zv.w, acc.w);
        }
    }
    #pragma unroll
    for (int mm = 8; mm < 32; mm <<= 1) {
        acc.x += __shfl_xor(acc.x, mm);
        acc.y += __shfl_xor(acc.y, mm);
        acc.z += __shfl_xor(acc.z, mm);
        acc.w += __shfl_xor(acc.w, mm);
    }
    if (g == 0) {
        float4 bb = reinterpret_cast<const float4*>(b)[c];
        float4 o;
        o.x = lrelu(acc.x + bb.x, slope_out);
        o.y = lrelu(acc.y + bb.y, slope_out);
        o.z = lrelu(acc.z + bb.z, slope_out);
        o.w = lrelu(acc.w + bb.w, slope_out);
        reinterpret_cast<float4*>(out)[(size_t)node * 8 + c] = o;
    }
}

__global__ __launch_bounds__(256) void pool_kernel(
    const float* __restrict__ h2, const int* __restrict__ gid, float* __restrict__ out)
{
    int g = blockIdx.x;
    int lo = 0, hi = NN;
    while (lo < hi) { int mid = (lo + hi) >> 1; if (gid[mid] < g) lo = mid + 1; else hi = mid; }
    int start = lo;
    hi = NN;
    while (lo < hi) { int mid = (lo + hi) >> 1; if (gid[mid] < g + 1) lo = mid + 1; else hi = mid; }
    int end = lo;
    int f = threadIdx.x & 31, r = threadIdx.x >> 5;
    float acc = 0.f;
    for (int n = start + r; n < end; n += 8) acc += h2[(size_t)n * F2 + f];
    __shared__ float red[256];
    red[threadIdx.x] = acc;
    __syncthreads();
    for (int st = 128; st >= 32; st >>= 1) {
        if (threadIdx.x < st) red[threadIdx.x] += red[threadIdx.x + st];
        __syncthreads();
    }
    if (threadIdx.x < 32) {
        float cnt = (float)(end - start);
        out[g * F2 + threadIdx.x] = red[threadIdx.x] / fmaxf(cnt, 1.0f);
    }
}

extern "C" void kernel_launch(void* const* d_in, const int* in_sizes, int n_in,
                              void* d_out, int out_size, void* d_ws, size_t ws_size,
                              hipStream_t stream)
{
    float* ws = (float*)d_ws;
    float* z1   = ws;                            // NN*64
    float* h1   = z1 + (size_t)NN * F1;          // NN*64
    float* z2   = h1 + (size_t)NN * F1;          // NN*32
    float* h2   = z2 + (size_t)NN * F2;          // NN*32
    float* el   = h2 + (size_t)NN * F2;          // NN
    float* er   = el + NN;                       // NN
    int* row_start = (int*)(er + NN);            // NN+1
    int* srcs      = row_start + NN + 1;         // NE
    int* hist      = srcs + NE;                  // NBK*NC
    int* btot      = hist + NBK * NC;            // NBK
    int* bstart    = btot + NBK;                 // NBK+1
    int2* part     = (int2*)(bstart + NBK + 1);  // NE int2

    MegaParams P;
    P.x   = (const float*)d_in[0];
    P.src = (const int*)d_in[1];
    P.dst = (const int*)d_in[2];
    P.gid = (const int*)d_in[3];
    P.W1  = (const float*)d_in[4];
    P.al1 = (const float*)d_in[5];
    P.ar1 = (const float*)d_in[6];
    P.b1  = (const float*)d_in[7];
    P.W2  = (const float*)d_in[8];
    P.al2 = (const float*)d_in[9];
    P.ar2 = (const float*)d_in[10];
    P.b2  = (const float*)d_in[11];
    P.out = (float*)d_out;
    P.z1 = z1; P.h1 = h1; P.z2 = z2; P.h2 = h2; P.el = el; P.er = er;
    P.row_start = row_start; P.srcs = srcs; P.hist = hist;
    P.btot = btot; P.bstart = bstart; P.part = part;

    void* args[] = { &P };
    hipError_t err = hipLaunchCooperativeKernel((void*)mega_kernel, dim3(NBLK),
                                                dim3(256), args, 0, stream);
    if (err != hipSuccess) {
        // fallback: proven multi-kernel pipeline (same math, same buffers)
        p1_hist_kernel<<<NC, 256, 0, stream>>>(P.dst, hist);
        p2a_scan_kernel<<<NBK, 256, 0, stream>>>(hist, btot);
        p2b_scan_kernel<<<1, 256, 0, stream>>>(btot, bstart, row_start);
        p3_part_kernel<<<NC, 256, 0, stream>>>(P.src, P.dst, hist, bstart, part);
        p4_fill_kernel<<<NBK, 256, 0, stream>>>(part, bstart, row_start, srcs);
        gemm1_kernel<<<NTILE1, 256, 0, stream>>>(P.x, P.W1, P.al1, P.ar1, z1, el, er);
        gat_agg64_kernel<<<(NN * 64 + 255) / 256, 256, 0, stream>>>(
            row_start, srcs, el, er, z1, P.b1, h1, 0.01f);
        gemm2_kernel<<<NTILE2, 256, 0, stream>>>(h1, P.W2, P.al2, P.ar2, z2, el, er);
        gat_agg32_kernel<<<(NN * 32 + 255) / 256, 256, 0, stream>>>(
            row_start, srcs, el, er, z2, P.b2, h2, 0.01f);
        pool_kernel<<<NG, 256, 0, stream>>>(h2, P.gid, P.out);
    }
}

// Round 9
// 273.735 us; speedup vs baseline: 3.3223x; 3.3223x over previous
//
#include <hip/hip_runtime.h>
#include <math.h>

#define NN 50000
#define NE 800000
#define NG 50
#define F0 128
#define F1 64
#define F2 32
#define NPB 256                  // nodes per bucket (bucket = dst >> 8)
#define NBK 196                  // ceil(NN/NPB)
#define CHUNK 4096
#define NC 196                   // ceil(NE/CHUNK)
#define NTILE1 1563              // ceil(NN/32)
#define NTILE2 782               // ceil(NN/64)

__device__ __forceinline__ float lrelu(float v, float slope) {
    return v > 0.0f ? v : v * slope;
}

// ==== k1: blocks [0,NC) = per-chunk dst-bucket histogram; rest = GEMM1 tiles.
// The two halves are data-independent; merged purely to save a dispatch.
__global__ __launch_bounds__(256) void k1_hist_gemm1_kernel(
    const int* __restrict__ dst, int* __restrict__ hist,
    const float* __restrict__ x, const float* __restrict__ W,
    const float* __restrict__ al, const float* __restrict__ ar,
    float* __restrict__ z, float* __restrict__ el, float* __restrict__ er)
{
    __shared__ float Ws[F0 * F1];     // 32 KB (hist aliases this)
    __shared__ float xs[32][F0];      // 16 KB
    int tid = threadIdx.x;

    if (blockIdx.x < NC) {
        int* h = (int*)Ws;
        int c = blockIdx.x;
        if (tid < NBK) h[tid] = 0;
        __syncthreads();
        int e0 = c * CHUNK;
        int e1 = (e0 + CHUNK < NE) ? e0 + CHUNK : NE;
        for (int e = e0 + tid; e < e1; e += 256)
            atomicAdd(&h[dst[e] >> 8], 1);
        __syncthreads();
        if (tid < NBK) hist[tid * NC + c] = h[tid];
        return;
    }

    int r0 = (blockIdx.x - NC) * 32;
    {
        const float4* W4 = reinterpret_cast<const float4*>(W);
        float4* Ws4 = reinterpret_cast<float4*>(Ws);
        #pragma unroll
        for (int i = 0; i < 8; ++i) Ws4[tid + i * 256] = W4[tid + i * 256];
    }
    {
        float4 zero = {0.f, 0.f, 0.f, 0.f};
        #pragma unroll
        for (int i = 0; i < 4; ++i) {
            int s = tid + i * 256;
            int row = s >> 5, c4 = s & 31;
            int grow = r0 + row;
            float4 v = (grow < NN)
                ? reinterpret_cast<const float4*>(x)[(size_t)grow * 32 + c4] : zero;
            *reinterpret_cast<float4*>(&xs[row][c4 * 4]) = v;
        }
    }
    __syncthreads();
    int j = tid & 63, rg = tid >> 6;
    float acc[8] = {0.f, 0.f, 0.f, 0.f, 0.f, 0.f, 0.f, 0.f};
    for (int k4 = 0; k4 < F0 / 4; ++k4) {
        float w0 = Ws[(k4 * 4 + 0) * F1 + j];
        float w1 = Ws[(k4 * 4 + 1) * F1 + j];
        float w2 = Ws[(k4 * 4 + 2) * F1 + j];
        float w3 = Ws[(k4 * 4 + 3) * F1 + j];
        #pragma unroll
        for (int r = 0; r < 8; ++r) {
            float4 xv = *reinterpret_cast<const float4*>(&xs[rg * 8 + r][k4 * 4]);
            acc[r] = fmaf(xv.x, w0, fmaf(xv.y, w1, fmaf(xv.z, w2, fmaf(xv.w, w3, acc[r]))));
        }
    }
    float a_l = al[j], a_r = ar[j];
    #pragma unroll
    for (int r = 0; r < 8; ++r) {
        int row = r0 + rg * 8 + r;
        if (row < NN) z[(size_t)row * F1 + j] = acc[r];
        float pl = acc[r] * a_l, pr = acc[r] * a_r;
        #pragma unroll
        for (int mm = 1; mm < 64; mm <<= 1) {
            pl += __shfl_xor(pl, mm);
            pr += __shfl_xor(pr, mm);
        }
        if (j == 0 && row < NN) { el[row] = pl; er[row] = pr; }
    }
}

// ==== p2a: per-bucket exclusive scan over chunks (in place); bucket totals out
__global__ __launch_bounds__(256) void p2a_scan_kernel(
    int* __restrict__ hist, int* __restrict__ btot)
{
    __shared__ int t[256];
    int b = blockIdx.x;
    int v = (threadIdx.x < NC) ? hist[b * NC + threadIdx.x] : 0;
    t[threadIdx.x] = v;
    __syncthreads();
    for (int off = 1; off < 256; off <<= 1) {
        int u = (threadIdx.x >= off) ? t[threadIdx.x - off] : 0;
        __syncthreads();
        t[threadIdx.x] += u;
        __syncthreads();
    }
    if (threadIdx.x < NC) hist[b * NC + threadIdx.x] = t[threadIdx.x] - v; // exclusive
    if (threadIdx.x == 255) btot[b] = t[255];
}

// ==== p3: partition edges into bucket-contiguous (src,dst); bstart recomputed
// in-LDS from btot (196-wide scan — cheap, saves the p2b dispatch).
__global__ __launch_bounds__(256) void p3_part_kernel(
    const int* __restrict__ src, const int* __restrict__ dst,
    const int* __restrict__ hist, const int* __restrict__ btot,
    int2* __restrict__ part)
{
    __shared__ int t[256];
    __shared__ int base[NBK];
    __shared__ int cnt[NBK];
    int tid = threadIdx.x;
    int c = blockIdx.x;
    int v = (tid < NBK) ? btot[tid] : 0;
    t[tid] = v;
    __syncthreads();
    for (int off = 1; off < 256; off <<= 1) {
        int u = (tid >= off) ? t[tid - off] : 0;
        __syncthreads();
        t[tid] += u;
        __syncthreads();
    }
    if (tid < NBK) {
        base[tid] = hist[tid * NC + c] + (t[tid] - v);   // chunk-exclusive + bucket base
        cnt[tid] = 0;
    }
    __syncthreads();
    int e0 = c * CHUNK;
    int e1 = (e0 + CHUNK < NE) ? e0 + CHUNK : NE;
    for (int e = e0 + tid; e < e1; e += 256) {
        int s = src[e], d = dst[e];
        int b = d >> 8;
        int r = atomicAdd(&cnt[b], 1);
        part[base[b] + r] = make_int2(s, d);
    }
}

// ==== p4: per-bucket rank -> row_start + srcs (dense region per block)
__global__ __launch_bounds__(256) void p4_fill_kernel(
    const int2* __restrict__ part, const int* __restrict__ btot,
    int* __restrict__ row_start, int* __restrict__ srcs)
{
    __shared__ int t[256];
    __shared__ int deg[NPB];
    __shared__ int off[NPB];
    __shared__ int cnt[NPB];
    int tid = threadIdx.x;
    int b = blockIdx.x;
    int v = (tid < NBK) ? btot[tid] : 0;
    t[tid] = v;
    __syncthreads();
    for (int o = 1; o < 256; o <<= 1) {
        int u = (tid >= o) ? t[tid - o] : 0;
        __syncthreads();
        t[tid] += u;
        __syncthreads();
    }
    int hi = t[b];                 // inclusive prefix at b
    int lo = hi - btot[b];         // exclusive
    if (b == 0 && tid == 0) row_start[NN] = NE;
    deg[tid] = 0;
    cnt[tid] = 0;
    __syncthreads();
    for (int i = lo + tid; i < hi; i += 256)
        atomicAdd(&deg[part[i].y & (NPB - 1)], 1);
    __syncthreads();
    int dv = deg[tid];
    off[tid] = dv;
    __syncthreads();
    for (int o = 1; o < 256; o <<= 1) {
        int u = (tid >= o) ? off[tid - o] : 0;
        __syncthreads();
        off[tid] += u;
        __syncthreads();
    }
    int ex = off[tid] - dv;
    __syncthreads();
    off[tid] = ex;
    __syncthreads();
    int node = b * NPB + tid;
    if (node < NN) row_start[node] = lo + ex;
    for (int i = lo + tid; i < hi; i += 256) {
        int2 e = part[i];
        int n = e.y & (NPB - 1);
        int r = atomicAdd(&cnt[n], 1);
        srcs[lo + off[n] + r] = e.x;
    }
}

// ==== fused attention aggregation (gather, no atomics), 8 edges in flight ====
__global__ __launch_bounds__(256) void gat_agg64_kernel(
    const int* __restrict__ row_start, const int* __restrict__ srcs,
    const float* __restrict__ el, const float* __restrict__ er,
    const float* __restrict__ z, const float* __restrict__ b,
    float* __restrict__ out, float slope_out)
{
    int node = (blockIdx.x * 256 + threadIdx.x) >> 6;
    if (node >= NN) return;
    int lane = threadIdx.x & 63;
    int g = lane >> 4, c = lane & 15;
    int beg = row_start[node], end = row_start[node + 1];
    float erd = er[node];

    int i0 = beg + lane;
    float v0 = -INFINITY;
    if (i0 < end) v0 = lrelu(el[srcs[i0]] + erd, 0.2f);
    float lm = v0;
    for (int i = i0 + 64; i < end; i += 64)
        lm = fmaxf(lm, lrelu(el[srcs[i]] + erd, 0.2f));
    #pragma unroll
    for (int mm = 1; mm < 64; mm <<= 1) lm = fmaxf(lm, __shfl_xor(lm, mm));

    float preg = 0.f, ls = 0.f;
    if (i0 < end) { preg = __expf(v0 - lm); ls = preg; }
    for (int i = i0 + 64; i < end; i += 64)
        ls += __expf(lrelu(el[srcs[i]] + erd, 0.2f) - lm);
    #pragma unroll
    for (int mm = 1; mm < 64; mm <<= 1) ls += __shfl_xor(ls, mm);
    float inv_s = (ls > 0.f) ? 1.0f / ls : 0.f;
    preg *= inv_s;   // pre-scaled; shfl'd values are final alphas for j<64

    const float4* z4 = reinterpret_cast<const float4*>(z);
    float4 acc = {0.f, 0.f, 0.f, 0.f};
    int ib = beg;
    for (; ib + 8 <= end; ib += 8) {
        int ia = ib + g, ic = ib + 4 + g;
        int ja = ia - beg, jc = ic - beg;
        float aa = __shfl(preg, ja & 63);
        float ac = __shfl(preg, jc & 63);
        int sna = srcs[ia], snc = srcs[ic];
        if (ja >= 64) aa = __expf(lrelu(el[sna] + erd, 0.2f) - lm) * inv_s;
        if (jc >= 64) ac = __expf(lrelu(el[snc] + erd, 0.2f) - lm) * inv_s;
        float4 zva = z4[(size_t)sna * 16 + c];
        float4 zvc = z4[(size_t)snc * 16 + c];
        acc.x = fmaf(aa, zva.x, fmaf(ac, zvc.x, acc.x));
        acc.y = fmaf(aa, zva.y, fmaf(ac, zvc.y, acc.y));
        acc.z = fmaf(aa, zva.z, fmaf(ac, zvc.z, acc.z));
        acc.w = fmaf(aa, zva.w, fmaf(ac, zvc.w, acc.w));
    }
    for (; ib < end; ib += 4) {
        int i = ib + g, jj = i - beg;
        float aa = __shfl(preg, jj & 63);
        if (i < end) {
            int sn = srcs[i];
            if (jj >= 64) aa = __expf(lrelu(el[sn] + erd, 0.2f) - lm) * inv_s;
            float4 zv = z4[(size_t)sn * 16 + c];
            acc.x = fmaf(aa, zv.x, acc.x);
            acc.y = fmaf(aa, zv.y, acc.y);
            acc.z = fmaf(aa, zv.z, acc.z);
            acc.w = fmaf(aa, zv.w, acc.w);
        }
    }
    #pragma unroll
    for (int mm = 16; mm < 64; mm <<= 1) {
        acc.x += __shfl_xor(acc.x, mm);
        acc.y += __shfl_xor(acc.y, mm);
        acc.z += __shfl_xor(acc.z, mm);
        acc.w += __shfl_xor(acc.w, mm);
    }
    if (g == 0) {
        float4 bb = reinterpret_cast<const float4*>(b)[c];
        float4 o;
        o.x = lrelu(acc.x + bb.x, slope_out);
        o.y = lrelu(acc.y + bb.y, slope_out);
        o.z = lrelu(acc.z + bb.z, slope_out);
        o.w = lrelu(acc.w + bb.w, slope_out);
        reinterpret_cast<float4*>(out)[(size_t)node * 16 + c] = o;
    }
}

__global__ __launch_bounds__(256) void gat_agg32_kernel(
    const int* __restrict__ row_start, const int* __restrict__ srcs,
    const float* __restrict__ el, const float* __restrict__ er,
    const float* __restrict__ z, const float* __restrict__ b,
    float* __restrict__ out, float slope_out)
{
    int node = (blockIdx.x * 256 + threadIdx.x) >> 5;
    if (node >= NN) return;
    int sub = threadIdx.x & 31;
    int base = threadIdx.x & 32;
    int g = sub >> 3, c = sub & 7;
    int beg = row_start[node], end = row_start[node + 1];
    float erd = er[node];

    int i0 = beg + sub;
    float v0 = -INFINITY;
    if (i0 < end) v0 = lrelu(el[srcs[i0]] + erd, 0.2f);
    float lm = v0;
    for (int i = i0 + 32; i < end; i += 32)
        lm = fmaxf(lm, lrelu(el[srcs[i]] + erd, 0.2f));
    #pragma unroll
    for (int mm = 1; mm < 32; mm <<= 1) lm = fmaxf(lm, __shfl_xor(lm, mm));

    float preg = 0.f, ls = 0.f;
    if (i0 < end) { preg = __expf(v0 - lm); ls = preg; }
    for (int i = i0 + 32; i < end; i += 32)
        ls += __expf(lrelu(el[srcs[i]] + erd, 0.2f) - lm);
    #pragma unroll
    for (int mm = 1; mm < 32; mm <<= 1) ls += __shfl_xor(ls, mm);
    float inv_s = (ls > 0.f) ? 1.0f / ls : 0.f;
    preg *= inv_s;

    const float4* z4 = reinterpret_cast<const float4*>(z);
    float4 acc = {0.f, 0.f, 0.f, 0.f};
    int ib = beg;
    for (; ib + 8 <= end; ib += 8) {
        int ia = ib + g, ic = ib + 4 + g;
        int ja = ia - beg, jc = ic - beg;
        float aa = __shfl(preg, base | (ja & 31));
        float ac = __shfl(preg, base | (jc & 31));
        int sna = srcs[ia], snc = srcs[ic];
        if (ja >= 32) aa = __expf(lrelu(el[sna] + erd, 0.2f) - lm) * inv_s;
        if (jc >= 32) ac = __expf(lrelu(el[snc] + erd, 0.2f) - lm) * inv_s;
        float4 zva = z4[(size_t)sna * 8 + c];
        float4 zvc = z4[(size_t)snc * 8 + c];
        acc.x = fmaf(aa, zva.x, fmaf(ac, zvc.x, acc.x));
        acc.y = fmaf(aa, zva.y, fmaf(ac, zvc.y, acc.y));
        acc.z = fmaf(aa, zva.z, fmaf(ac, zvc.z, acc.z));
        acc.w = fmaf(aa, zva.w, fmaf(ac, zvc.w, acc.w));
    }
    for (; ib < end; ib += 4) {
        int i = ib + g, jj = i - beg;
        float aa = __shfl(preg, base | (jj & 31));
        if (i < end) {
            int sn = srcs[i];
            if (jj >= 32) aa = __expf(lrelu(el[sn] + erd, 0.2f) - lm) * inv_s;
            float4 zv = z4[(size_t)sn * 8 + c];
            acc.x = fmaf(aa, zv.x, acc.x);
            acc.y = fmaf(aa, zv.y, acc.y);
            acc.z = fmaf(aa, zv.z, acc.z);
            acc.w = fmaf(aa, zv.w, acc.w);
        }
    }
    #pragma unroll
    for (int mm = 8; mm < 32; mm <<= 1) {
        acc.x += __shfl_xor(acc.x, mm);
        acc.y += __shfl_xor(acc.y, mm);
        acc.z += __shfl_xor(acc.z, mm);
        acc.w += __shfl_xor(acc.w, mm);
    }
    if (g == 0) {
        float4 bb = reinterpret_cast<const float4*>(b)[c];
        float4 o;
        o.x = lrelu(acc.x + bb.x, slope_out);
        o.y = lrelu(acc.y + bb.y, slope_out);
        o.z = lrelu(acc.z + bb.z, slope_out);
        o.w = lrelu(acc.w + bb.w, slope_out);
        reinterpret_cast<float4*>(out)[(size_t)node * 8 + c] = o;
    }
}

// ==== GEMM2: register-blocked 64-row tiles
__global__ __launch_bounds__(256) void gemm2_kernel(
    const float* __restrict__ h, const float* __restrict__ W,
    const float* __restrict__ al, const float* __restrict__ ar,
    float* __restrict__ z, float* __restrict__ el, float* __restrict__ er)
{
    __shared__ float Ws[F1 * F2];
    __shared__ float xs[64][F1];
    int tid = threadIdx.x;
    int r0 = blockIdx.x * 64;
    {
        const float4* W4 = reinterpret_cast<const float4*>(W);
        float4* Ws4 = reinterpret_cast<float4*>(Ws);
        #pragma unroll
        for (int i = 0; i < 2; ++i) Ws4[tid + i * 256] = W4[tid + i * 256];
    }
    {
        float4 zero = {0.f, 0.f, 0.f, 0.f};
        #pragma unroll
        for (int i = 0; i < 4; ++i) {
            int s = tid + i * 256;
            int row = s >> 4, c4 = s & 15;
            int grow = r0 + row;
            float4 v = (grow < NN)
                ? reinterpret_cast<const float4*>(h)[(size_t)grow * 16 + c4] : zero;
            *reinterpret_cast<float4*>(&xs[row][c4 * 4]) = v;
        }
    }
    __syncthreads();
    int j = tid & 31, rg = tid >> 5;
    float acc[8] = {0.f, 0.f, 0.f, 0.f, 0.f, 0.f, 0.f, 0.f};
    for (int k4 = 0; k4 < F1 / 4; ++k4) {
        float w0 = Ws[(k4 * 4 + 0) * F2 + j];
        float w1 = Ws[(k4 * 4 + 1) * F2 + j];
        float w2 = Ws[(k4 * 4 + 2) * F2 + j];
        float w3 = Ws[(k4 * 4 + 3) * F2 + j];
        #pragma unroll
        for (int r = 0; r < 8; ++r) {
            float4 xv = *reinterpret_cast<const float4*>(&xs[rg * 8 + r][k4 * 4]);
            acc[r] = fmaf(xv.x, w0, fmaf(xv.y, w1, fmaf(xv.z, w2, fmaf(xv.w, w3, acc[r]))));
        }
    }
    float a_l = al[j], a_r = ar[j];
    #pragma unroll
    for (int r = 0; r < 8; ++r) {
        int row = r0 + rg * 8 + r;
        if (row < NN) z[(size_t)row * F2 + j] = acc[r];
        float pl = acc[r] * a_l, pr = acc[r] * a_r;
        #pragma unroll
        for (int mm = 1; mm < 32; mm <<= 1) {
            pl += __shfl_xor(pl, mm);
            pr += __shfl_xor(pr, mm);
        }
        if (j == 0 && row < NN) { el[row] = pl; er[row] = pr; }
    }
}

// ==== per-graph mean pool (graph_id sorted); one block per graph
__global__ __launch_bounds__(256) void pool_kernel(
    const float* __restrict__ h2, const int* __restrict__ gid, float* __restrict__ out)
{
    int g = blockIdx.x;
    int lo = 0, hi = NN;
    while (lo < hi) { int mid = (lo + hi) >> 1; if (gid[mid] < g) lo = mid + 1; else hi = mid; }
    int start = lo;
    hi = NN;
    while (lo < hi) { int mid = (lo + hi) >> 1; if (gid[mid] < g + 1) lo = mid + 1; else hi = mid; }
    int end = lo;
    int f = threadIdx.x & 31, r = threadIdx.x >> 5;
    float acc = 0.f;
    for (int n = start + r; n < end; n += 8) acc += h2[(size_t)n * F2 + f];
    __shared__ float red[256];
    red[threadIdx.x] = acc;
    __syncthreads();
    for (int st = 128; st >= 32; st >>= 1) {
        if (threadIdx.x < st) red[threadIdx.x] += red[threadIdx.x + st];
        __syncthreads();
    }
    if (threadIdx.x < 32) {
        float cnt = (float)(end - start);
        out[g * F2 + threadIdx.x] = red[threadIdx.x] / fmaxf(cnt, 1.0f);
    }
}

extern "C" void kernel_launch(void* const* d_in, const int* in_sizes, int n_in,
                              void* d_out, int out_size, void* d_ws, size_t ws_size,
                              hipStream_t stream)
{
    const float* x   = (const float*)d_in[0];
    const int*   src = (const int*)d_in[1];
    const int*   dst = (const int*)d_in[2];
    const int*   gid = (const int*)d_in[3];
    const float* W1  = (const float*)d_in[4];
    const float* al1 = (const float*)d_in[5];
    const float* ar1 = (const float*)d_in[6];
    const float* b1  = (const float*)d_in[7];
    const float* W2  = (const float*)d_in[8];
    const float* al2 = (const float*)d_in[9];
    const float* ar2 = (const float*)d_in[10];
    const float* b2  = (const float*)d_in[11];
    float* out = (float*)d_out;

    float* ws   = (float*)d_ws;
    float* z1   = ws;                            // NN*64
    float* h1   = z1 + (size_t)NN * F1;          // NN*64
    float* z2   = h1 + (size_t)NN * F1;          // NN*32
    float* h2   = z2 + (size_t)NN * F2;          // NN*32
    float* el   = h2 + (size_t)NN * F2;          // NN
    float* er   = el + NN;                       // NN
    int* row_start = (int*)(er + NN);            // NN+1
    int* srcs      = row_start + NN + 1;         // NE
    int* hist      = srcs + NE;                  // NBK*NC
    int* btot      = hist + NBK * NC;            // NBK (+pad to even)
    int2* part     = (int2*)(btot + NBK + 2);    // NE int2

    // d1: per-chunk histogram (blocks 0..NC-1) || GEMM1 (blocks NC..NC+NTILE1-1)
    k1_hist_gemm1_kernel<<<NC + NTILE1, 256, 0, stream>>>(
        dst, hist, x, W1, al1, ar1, z1, el, er);
    // d2: per-bucket exclusive scan over chunks
    p2a_scan_kernel<<<NBK, 256, 0, stream>>>(hist, btot);
    // d3: partition into bucket-contiguous (src,dst)
    p3_part_kernel<<<NC, 256, 0, stream>>>(src, dst, hist, btot, part);
    // d4: per-bucket rank -> row_start + srcs
    p4_fill_kernel<<<NBK, 256, 0, stream>>>(part, btot, row_start, srcs);
    // d5: GAT layer-1 aggregation
    gat_agg64_kernel<<<(NN * 64 + 255) / 256, 256, 0, stream>>>(
        row_start, srcs, el, er, z1, b1, h1, 0.01f);
    // d6: GEMM2
    gemm2_kernel<<<NTILE2, 256, 0, stream>>>(h1, W2, al2, ar2, z2, el, er);
    // d7: GAT layer-2 aggregation
    gat_agg32_kernel<<<(NN * 32 + 255) / 256, 256, 0, stream>>>(
        row_start, srcs, el, er, z2, b2, h2, 0.01f);
    // d8: per-graph mean pool
    pool_kernel<<<NG, 256, 0, stream>>>(h2, gid, out);
}